// Round 9
// baseline (468.223 us; speedup 1.0000x reference)
//
#include <hip/hip_runtime.h>

#define NB 32      // B
#define LL 256     // L
#define LQn 128    // LQ
#define Dv 41
#define Cc 82
#define CP 84      // padded channel count
#define ET 128
#define NH 128
#define TNH 384

// workspace layout (float units)
#define OFF_QALL 0
#define OFF_KALL (OFF_QALL + NB*LQn*ET)        // q_all: 524288
#define OFF_XPAD (OFF_KALL + NB*LL*ET)         // k_all: 1048576
#define OFF_WCT  (OFF_XPAD + NB*LL*CP)         // x_pad: 688128
#define OFF_WHH2 (OFF_WCT + CP*768)            // WcT: 64512
#define OFF_ATT  (OFF_WHH2 + 2*64*TNH)         // whh4T [dir][16][384][4] uints: 49152
#define OFF_XF   (OFF_ATT + NB*LQn*CP)         // att: 344064
#define OFF_XB   (OFF_XF + NB*LQn*TNH)
#define OFF_HCAT (OFF_XB + NB*LQn*TNH)
#define OFF_WQT  (OFF_HCAT + NB*LQn*2*NH)
#define OFF_WKT  (OFF_WQT + ET*ET)

typedef _Float16 h2_t __attribute__((ext_vector_type(2)));

__device__ __forceinline__ float quad_xor1_add(float x) {
  int y = __builtin_amdgcn_mov_dpp(__float_as_int(x), 0xB1, 0xF, 0xF, true);
  return x + __int_as_float(y);
}
__device__ __forceinline__ float quad_xor2_add(float x) {
  int y = __builtin_amdgcn_mov_dpp(__float_as_int(x), 0x4E, 0xF, 0xF, true);
  return x + __int_as_float(y);
}
__device__ __forceinline__ float fast_sigmoid(float x) {
  return 1.f / (1.f + __expf(-x));
}
__device__ __forceinline__ float fast_tanh(float x) {
  x = fmaxf(fminf(x, 15.f), -15.f);
  float e2 = __expf(2.f * x);
  return (e2 - 1.f) / (e2 + 1.f);
}
__device__ __forceinline__ float fdot2f(unsigned int a, unsigned int b, float acc) {
  return __builtin_amdgcn_fdot2(__builtin_bit_cast(h2_t, a),
                                __builtin_bit_cast(h2_t, b), acc, false);
}

// ---------------- K0: preprocessing ----------------
__global__ __launch_bounds__(256) void k0_prep(
    const float* __restrict__ x, const float* __restrict__ Wq,
    const float* __restrict__ Wk, const float* __restrict__ Wo,
    const float* __restrict__ bo,
    const float* __restrict__ wihf, const float* __restrict__ bihf,
    const float* __restrict__ wihb, const float* __restrict__ bihb,
    const float* __restrict__ whhf, const float* __restrict__ whhb,
    float* ws) {
  int bid = blockIdx.x;
  int t = threadIdx.x;
  if (bid < 2688) {                       // x_pad: 32*256*84 = 688128
    int idx = bid*256 + t;
    int c = idx % CP; int row = idx / CP;
    float v = (c < Cc) ? x[row*Cc + c] : 0.f;
    ws[OFF_XPAD + idx] = v;
  } else if (bid < 2940) {                // WcT: 768*84 = 64512
    int idx = (bid-2688)*256 + t;
    int c = idx % CP; int j = idx / CP;
    const float* wih = (j < TNH) ? wihf : wihb;
    const float* bih = (j < TNH) ? bihf : bihb;
    int jj = (j < TNH) ? j : j - TNH;
    float acc = 0.f;
    if (c < Cc) {
      for (int k = 0; k < NH; k++) acc = fmaf(wih[jj*NH+k], Wo[k*Cc + c], acc);
    } else if (c == Cc) {
      for (int k = 0; k < NH; k++) acc = fmaf(wih[jj*NH+k], bo[k], acc);
      acc += bih[jj];
    }
    ws[OFF_WCT + c*768 + j] = acc;
  } else if (bid < 3132) {                // whh4T: [dir][16][384][4] uints = 49152
    int idx = (bid-2940)*256 + t;
    int dir = idx / 24576;
    int r = idx % 24576;
    int u = r & 3;
    int tt = (r >> 2) % 384;            // row (output j)
    int k2g = (r >> 2) / 384;           // chunk
    int k2 = k2g*4 + u;                 // packed-half2 index along k
    const float* whh = dir ? whhb : whhf;
    float a = whh[tt*NH + 2*k2];
    float b = whh[tt*NH + 2*k2 + 1];
    union { _Float16 h[2]; unsigned int uu; } pk;
    pk.h[0] = (_Float16)a; pk.h[1] = (_Float16)b;
    ((unsigned int*)ws)[OFF_WHH2 + idx] = pk.uu;
  } else {                                // WqT/WkT: 2*16384
    int idx = (bid-3132)*256 + t;
    int j = idx & 127; int k = (idx >> 7) & 127; int w = idx >> 14;
    const float* W = w ? Wk : Wq;
    ws[(w ? OFF_WKT : OFF_WQT) + k*ET + j] = W[j*ET + k];
  }
}

// ---------------- K1: time-embed + projection ----------------
__global__ __launch_bounds__(256, 2) void k1_embed_proj(
    const float* __restrict__ query, const float* __restrict__ tsteps,
    const float* __restrict__ bq, const float* __restrict__ bk,
    float* ws) {
  __shared__ float emb[64*132];
  __shared__ float wt[64*132];
  int bid = blockIdx.x, t = threadIdx.x;
  bool isQ = bid < 64;
  int rowbase = isQ ? bid*64 : (bid-64)*64;

  for (int ii = 0; ii < 16; ii++) {
    int p = t + ii*256;
    int r = p >> 6, i = p & 63;
    int grow = rowbase + r;
    float pos = isQ ? query[grow] : tsteps[grow];
    float dv = __expf(-(float)(2*i) * (2.302585092994046f/128.f));
    float ang = 48.f * pos * dv;
    float sv, cv; __sincosf(ang, &sv, &cv);
    emb[r*132 + 2*i]     = sv;
    emb[r*132 + 2*i + 1] = cv;
  }

  const float* wtg  = ws + (isQ ? OFF_WQT : OFF_WKT);
  const float* bias = isQ ? bq : bk;
  int cq = t & 31, rh = t >> 5;
  float acc[8][4];
  for (int ri = 0; ri < 8; ri++)
    for (int u = 0; u < 4; u++) acc[ri][u] = bias[cq*4 + u];

  for (int kk = 0; kk < 128; kk += 64) {
    __syncthreads();
    for (int ii = 0; ii < 32; ii++) {
      int idx = t + ii*256;
      int kl = idx >> 7, j = idx & 127;
      wt[kl*132 + j] = wtg[(kk+kl)*ET + j];
    }
    __syncthreads();
    for (int k4 = 0; k4 < 16; k4++) {
      float wv[4][4];
      #pragma unroll
      for (int u = 0; u < 4; u++) {
        float4 w4 = *(const float4*)&wt[(k4*4+u)*132 + cq*4];
        wv[u][0]=w4.x; wv[u][1]=w4.y; wv[u][2]=w4.z; wv[u][3]=w4.w;
      }
      #pragma unroll
      for (int ri = 0; ri < 8; ri++) {
        float4 e4 = *(const float4*)&emb[(rh*8+ri)*132 + kk + k4*4];
        float ev[4] = {e4.x, e4.y, e4.z, e4.w};
        #pragma unroll
        for (int u = 0; u < 4; u++)
          #pragma unroll
          for (int jj = 0; jj < 4; jj++)
            acc[ri][jj] = fmaf(ev[u], wv[u][jj], acc[ri][jj]);
      }
    }
  }
  int secbase = isQ ? OFF_QALL : OFF_KALL;
  for (int ri = 0; ri < 8; ri++) {
    int grow = rowbase + rh*8 + ri;
    float4 o4 = {acc[ri][0], acc[ri][1], acc[ri][2], acc[ri][3]};
    *(float4*)&ws[secbase + grow*ET + cq*4] = o4;
  }
}

// ---------------- K2: attention (scores -> e -> S -> att) ----------------
__global__ __launch_bounds__(256, 2) void k2_attn(float* ws) {
  __shared__ float sS[16*CP];
  __shared__ float se[16*260];
  int bb = blockIdx.x >> 3, qt = blockIdx.x & 7;
  int t = threadIdx.x;
  int lane = t & 63, wv_ = t >> 6;
  int r4 = lane >> 2, seg = lane & 3;

  float4 qreg[8];
  const float* qrow = ws + OFF_QALL + (bb*LQn + qt*16 + r4)*ET + seg*32;
  #pragma unroll
  for (int u = 0; u < 8; u++) qreg[u] = *(const float4*)&qrow[u*4];

  const float* kb = ws + OFF_KALL + bb*LL*ET;
  #pragma unroll 2
  for (int l = wv_*64; l < wv_*64 + 64; l++) {
    const float* krow = kb + l*ET + seg*32;
    float a0=0.f, a1=0.f, a2=0.f, a3=0.f;
    #pragma unroll
    for (int u = 0; u < 8; u++) {
      float4 kv = *(const float4*)&krow[u*4];
      float* aa = (u&3)==0 ? &a0 : (u&3)==1 ? &a1 : (u&3)==2 ? &a2 : &a3;
      *aa = fmaf(qreg[u].x, kv.x, *aa);
      *aa = fmaf(qreg[u].y, kv.y, *aa);
      *aa = fmaf(qreg[u].z, kv.z, *aa);
      *aa = fmaf(qreg[u].w, kv.w, *aa);
    }
    float a = (a0+a1) + (a2+a3);
    a = quad_xor1_add(a);
    a = quad_xor2_add(a);
    if (seg == 0) se[r4*260 + l] = a;
  }
  __syncthreads();

  {
    int rr = t >> 4, j0 = t & 15;
    float m = -1e30f;
    for (int i = 0; i < 16; i++) m = fmaxf(m, se[rr*260 + j0 + 16*i]);
    for (int msk = 1; msk < 16; msk <<= 1) m = fmaxf(m, __shfl_xor(m, msk));
    for (int i = 0; i < 16; i++) {
      int c0 = j0 + 16*i;
      se[rr*260 + c0] = __expf((se[rr*260 + c0] - m) * 0.08838834764831845f);
    }
  }
  __syncthreads();

  int cq = t & 31, rg = t >> 5;
  if (cq < 21) {
    float acc[2][4] = {{0,0,0,0},{0,0,0,0}};
    const float* xb_ = ws + OFF_XPAD + bb*LL*CP;
    for (int l4 = 0; l4 < 64; l4++) {
      float4 e0 = *(const float4*)&se[(rg*2+0)*260 + l4*4];
      float4 e1 = *(const float4*)&se[(rg*2+1)*260 + l4*4];
      float ev[2][4] = {{e0.x,e0.y,e0.z,e0.w},{e1.x,e1.y,e1.z,e1.w}};
      #pragma unroll
      for (int v = 0; v < 4; v++) {
        float4 x4 = *(const float4*)&xb_[(l4*4+v)*CP + cq*4];
        float xv[4] = {x4.x,x4.y,x4.z,x4.w};
        #pragma unroll
        for (int ri = 0; ri < 2; ri++)
          #pragma unroll
          for (int cu = 0; cu < 4; cu++)
            acc[ri][cu] = fmaf(ev[ri][v], xv[cu], acc[ri][cu]);
      }
    }
    for (int ri = 0; ri < 2; ri++) {
      float4 o4 = {acc[ri][0],acc[ri][1],acc[ri][2],acc[ri][3]};
      *(float4*)&sS[(rg*2+ri)*CP + cq*4] = o4;
    }
  }
  __syncthreads();

  for (int idx = t; idx < 16*41; idx += 256) {
    int rr = idx / 41, c = idx % 41;
    sS[rr*CP + c] = sS[rr*CP + c] / sS[rr*CP + 41 + c];
  }
  __syncthreads();
  for (int idx = t; idx < 16*43; idx += 256) {
    int rr = idx / 43, c = 41 + idx % 43;
    sS[rr*CP + c] = (c < 83) ? 1.f : 0.f;
  }
  __syncthreads();
  int base = OFF_ATT + (bb*LQn + qt*16)*CP;
  for (int idx = t; idx < 16*CP; idx += 256) ws[base + idx] = sS[idx];
}

// ---------------- K3: xproj = att @ WcT ----------------
__global__ __launch_bounds__(256, 2) void k3_xproj(float* ws) {
  __shared__ float at[64*CP];
  int mblk = blockIdx.x / 6, jblk = blockIdx.x % 6;
  int t = threadIdx.x;
  for (int ii = 0; ii < 21; ii++) {
    int idx = t + ii*256;
    at[idx] = ws[OFF_ATT + mblk*64*CP + idx];
  }
  __syncthreads();
  int j4l = t & 31, rg = t >> 5;
  float acc[8][4] = {};
  const float* wct = ws + OFF_WCT;
  int jg = jblk*128 + j4l*4;
  for (int c4 = 0; c4 < 21; c4++) {
    float wv[4][4];
    #pragma unroll
    for (int u = 0; u < 4; u++) {
      float4 w4 = *(const float4*)&wct[(c4*4+u)*768 + jg];
      wv[u][0]=w4.x; wv[u][1]=w4.y; wv[u][2]=w4.z; wv[u][3]=w4.w;
    }
    #pragma unroll
    for (int ri = 0; ri < 8; ri++) {
      float4 a4 = *(const float4*)&at[(rg*8+ri)*CP + c4*4];
      float av[4] = {a4.x,a4.y,a4.z,a4.w};
      #pragma unroll
      for (int u = 0; u < 4; u++)
        #pragma unroll
        for (int jj = 0; jj < 4; jj++)
          acc[ri][jj] = fmaf(av[u], wv[u][jj], acc[ri][jj]);
    }
  }
  float* dst = ws + (jblk < 3 ? OFF_XF : OFF_XB);
  int col = (jblk % 3)*128 + j4l*4;
  for (int ri = 0; ri < 8; ri++) {
    int row = mblk*64 + rg*8 + ri;
    float4 o4 = {acc[ri][0],acc[ri][1],acc[ri][2],acc[ri][3]};
    *(float4*)&dst[row*TNH + col] = o4;
  }
}

// ---------------- K4: bidirectional GRU ----------------
// 64 blocks = (b, dir), 384 thr. One barrier/step. Weights streamed from
// L2 as 16 coalesced dwordx4 per thread per step ([16][384][4] layout,
// unroll-4 chunks -> no 64-reg array, no spill/remat). x prefetched a full
// step ahead (issued top-of-step, consumed after NEXT barrier).
__global__ __launch_bounds__(384, 1) void k4_gru(
    const float* __restrict__ bhhf, const float* __restrict__ bhhb,
    float* ws) {
  __shared__ float gh[2][TNH];
  int bb = blockIdx.x >> 1, dir = blockIdx.x & 1;
  int t = threadIdx.x, lane = t & 63;
  int j0 = 2*lane;
  const uint4* wg4 = (const uint4*)((const unsigned int*)ws + OFF_WHH2 + dir*24576);
  const float* bhh = dir ? bhhb : bhhf;
  const float* xp = ws + (dir ? OFF_XB : OFF_XF) + bb*LQn*TNH;
  float* hc = ws + OFF_HCAT + bb*LQn*2*NH + dir*NH;

  float2 brv = *(const float2*)&bhh[j0];
  float2 bzv = *(const float2*)&bhh[NH + j0];
  float2 bnv = *(const float2*)&bhh[2*NH + j0];

  float h0 = 0.f, h1 = 0.f;
  unsigned int h2own = 0;

  int ti = dir ? (LQn-1) : 0;
  float2 xr = *(const float2*)&xp[ti*TNH + j0];
  float2 xz = *(const float2*)&xp[ti*TNH + NH + j0];
  float2 xn = *(const float2*)&xp[ti*TNH + 2*NH + j0];

  for (int step = 0; step < LQn; step++) {
    int buf = step & 1;

    // (1) prefetch next step's x FIRST — ~1.5 steps of latency cover
    int tin = dir ? (ti > 0 ? ti-1 : 0) : (ti < LQn-1 ? ti+1 : LQn-1);
    float2 xrn = *(const float2*)&xp[tin*TNH + j0];
    float2 xzn = *(const float2*)&xp[tin*TNH + NH + j0];
    float2 xnn = *(const float2*)&xp[tin*TNH + 2*NH + j0];

    // (2) gh[t] = Whh[t,:] . h  — weights streamed from L2, chunked
    float a0 = 0.f, a1 = 0.f;
    #pragma unroll 4
    for (int c = 0; c < 16; c++) {
      uint4 w = wg4[c*384 + t];
      unsigned int hv0 = (unsigned int)__builtin_amdgcn_readlane((int)h2own, 4*c+0);
      unsigned int hv1 = (unsigned int)__builtin_amdgcn_readlane((int)h2own, 4*c+1);
      unsigned int hv2 = (unsigned int)__builtin_amdgcn_readlane((int)h2own, 4*c+2);
      unsigned int hv3 = (unsigned int)__builtin_amdgcn_readlane((int)h2own, 4*c+3);
      a0 = fdot2f(hv0, w.x, a0);
      a1 = fdot2f(hv1, w.y, a1);
      a0 = fdot2f(hv2, w.z, a0);
      a1 = fdot2f(hv3, w.w, a1);
    }
    gh[buf][t] = a0 + a1;

    __syncthreads();

    // (3) gate math, redundant per-wave (j-pair 2*lane, 2*lane+1)
    float2 ghr = *(const float2*)&gh[buf][j0];
    float2 ghz = *(const float2*)&gh[buf][NH + j0];
    float2 ghn = *(const float2*)&gh[buf][2*NH + j0];

    float r0 = fast_sigmoid(xr.x + ghr.x + brv.x);
    float r1 = fast_sigmoid(xr.y + ghr.y + brv.y);
    float z0 = fast_sigmoid(xz.x + ghz.x + bzv.x);
    float z1 = fast_sigmoid(xz.y + ghz.y + bzv.y);
    float n0 = fast_tanh(xn.x + r0*(ghn.x + bnv.x));
    float n1 = fast_tanh(xn.y + r1*(ghn.y + bnv.y));
    h0 = (1.f - z0)*n0 + z0*h0;
    h1 = (1.f - z1)*n1 + z1*h1;

    union { _Float16 h[2]; unsigned int u; } pk;
    pk.h[0] = (_Float16)h0; pk.h[1] = (_Float16)h1;
    h2own = pk.u;

    if (t < 64) {
      float2 o2 = {h0, h1};
      *(float2*)&hc[ti*2*NH + j0] = o2;
    }

    xr = xrn; xz = xzn; xn = xnn;
    ti = tin;
  }
}

// ---------------- K5: final MLP ----------------
__global__ __launch_bounds__(256, 2) void k5_mlp(
    const float* __restrict__ W1, const float* __restrict__ b1,
    const float* __restrict__ W2, const float* __restrict__ b2,
    const float* __restrict__ ws, float* __restrict__ out) {
  __shared__ float hl[32*264];
  __shared__ float hid[32*52];
  int t = threadIdx.x;
  int rowbase = blockIdx.x * 32;
  for (int ii = 0; ii < 32; ii++) {
    int idx = t + ii*256;
    int r = idx >> 8, c = idx & 255;
    hl[r*264 + c] = ws[OFF_HCAT + (rowbase + r)*256 + c];
  }
  __syncthreads();
  int r = t & 31, mg = t >> 5;
  float acc[7];
  #pragma unroll
  for (int im = 0; im < 7; im++) {
    int m = mg + 8*im;
    acc[im] = (m < 50) ? b1[m] : 0.f;
  }
  for (int k4 = 0; k4 < 64; k4++) {
    float4 h4 = *(const float4*)&hl[r*264 + k4*4];
    #pragma unroll
    for (int im = 0; im < 7; im++) {
      int m = mg + 8*im;
      if (m < 50) {
        float4 w4 = *(const float4*)&W1[m*256 + k4*4];
        acc[im] = fmaf(h4.x, w4.x, acc[im]);
        acc[im] = fmaf(h4.y, w4.y, acc[im]);
        acc[im] = fmaf(h4.z, w4.z, acc[im]);
        acc[im] = fmaf(h4.w, w4.w, acc[im]);
      }
    }
  }
  #pragma unroll
  for (int im = 0; im < 7; im++) {
    int m = mg + 8*im;
    if (m < 50) hid[r*52 + m] = fmaxf(acc[im], 0.f);
  }
  __syncthreads();
  int og = mg;
  float a4[4];
  #pragma unroll
  for (int u = 0; u < 4; u++) a4[u] = b2[og*4 + u];
  for (int m = 0; m < 50; m++) {
    float hv = hid[r*52 + m];
    #pragma unroll
    for (int u = 0; u < 4; u++)
      a4[u] = fmaf(hv, W2[(og*4+u)*50 + m], a4[u]);
  }
  float4 o4 = {a4[0], a4[1], a4[2], a4[3]};
  *(float4*)&out[(rowbase + r)*32 + og*4] = o4;
}

extern "C" void kernel_launch(void* const* d_in, const int* in_sizes, int n_in,
                              void* d_out, int out_size, void* d_ws, size_t ws_size,
                              hipStream_t stream) {
  (void)in_sizes; (void)n_in; (void)out_size; (void)ws_size;
  const float* x      = (const float*)d_in[0];
  const float* tsteps = (const float*)d_in[1];
  const float* query  = (const float*)d_in[2];
  const float* Wq     = (const float*)d_in[3];
  const float* bq     = (const float*)d_in[4];
  const float* Wk     = (const float*)d_in[5];
  const float* bk     = (const float*)d_in[6];
  const float* Wo     = (const float*)d_in[7];
  const float* bo     = (const float*)d_in[8];
  const float* wihf   = (const float*)d_in[9];
  const float* whhf   = (const float*)d_in[10];
  const float* bihf   = (const float*)d_in[11];
  const float* bhhf   = (const float*)d_in[12];
  const float* wihb   = (const float*)d_in[13];
  const float* whhb   = (const float*)d_in[14];
  const float* bihb   = (const float*)d_in[15];
  const float* bhhb   = (const float*)d_in[16];
  const float* W1     = (const float*)d_in[17];
  const float* b1     = (const float*)d_in[18];
  const float* W2     = (const float*)d_in[19];
  const float* b2     = (const float*)d_in[20];
  float* ws = (float*)d_ws;

  k0_prep<<<3260, 256, 0, stream>>>(x, Wq, Wk, Wo, bo, wihf, bihf, wihb, bihb, whhf, whhb, ws);
  k1_embed_proj<<<192, 256, 0, stream>>>(query, tsteps, bq, bk, ws);
  k2_attn<<<256, 256, 0, stream>>>(ws);
  k3_xproj<<<384, 256, 0, stream>>>(ws);
  k4_gru<<<64, 384, 0, stream>>>(bhhf, bhhb, ws);
  k5_mlp<<<128, 256, 0, stream>>>(W1, b1, W2, b2, ws, (float*)d_out);
}

// Round 10
// 387.370 us; speedup vs baseline: 1.2087x; 1.2087x over previous
//
#include <hip/hip_runtime.h>

#define NB 32      // B
#define LL 256     // L
#define LQn 128    // LQ
#define Dv 41
#define Cc 82
#define CP 84      // padded channel count
#define ET 128
#define NH 128
#define TNH 384

// workspace layout (float units)
#define OFF_QALL 0
#define OFF_KALL (OFF_QALL + NB*LQn*ET)        // q_all: 524288
#define OFF_XPAD (OFF_KALL + NB*LL*ET)         // k_all: 1048576
#define OFF_WCT  (OFF_XPAD + NB*LL*CP)         // x_pad: 688128
#define OFF_WHH2 (OFF_WCT + CP*768)            // WcT: 64512
#define OFF_ATT  (OFF_WHH2 + 2*64*TNH)         // whh4T [dir][16][384][4] uints: 49152
#define OFF_XF   (OFF_ATT + NB*LQn*CP)         // att: 344064
#define OFF_XB   (OFF_XF + NB*LQn*TNH)
#define OFF_HCAT (OFF_XB + NB*LQn*TNH)
#define OFF_WQT  (OFF_HCAT + NB*LQn*2*NH)
#define OFF_WKT  (OFF_WQT + ET*ET)

typedef _Float16 h2_t __attribute__((ext_vector_type(2)));

__device__ __forceinline__ float quad_xor1_add(float x) {
  int y = __builtin_amdgcn_mov_dpp(__float_as_int(x), 0xB1, 0xF, 0xF, true);
  return x + __int_as_float(y);
}
__device__ __forceinline__ float quad_xor2_add(float x) {
  int y = __builtin_amdgcn_mov_dpp(__float_as_int(x), 0x4E, 0xF, 0xF, true);
  return x + __int_as_float(y);
}
__device__ __forceinline__ float fast_sigmoid(float x) {
  return 1.f / (1.f + __expf(-x));
}
__device__ __forceinline__ float fast_tanh(float x) {
  x = fmaxf(fminf(x, 15.f), -15.f);
  float e2 = __expf(2.f * x);
  return (e2 - 1.f) / (e2 + 1.f);
}
__device__ __forceinline__ float fdot2f(unsigned int a, unsigned int b, float acc) {
  return __builtin_amdgcn_fdot2(__builtin_bit_cast(h2_t, a),
                                __builtin_bit_cast(h2_t, b), acc, false);
}

// ---------------- K0: preprocessing ----------------
__global__ __launch_bounds__(256) void k0_prep(
    const float* __restrict__ x, const float* __restrict__ Wq,
    const float* __restrict__ Wk, const float* __restrict__ Wo,
    const float* __restrict__ bo,
    const float* __restrict__ wihf, const float* __restrict__ bihf,
    const float* __restrict__ wihb, const float* __restrict__ bihb,
    const float* __restrict__ whhf, const float* __restrict__ whhb,
    float* ws) {
  int bid = blockIdx.x;
  int t = threadIdx.x;
  if (bid < 2688) {                       // x_pad: 32*256*84 = 688128
    int idx = bid*256 + t;
    int c = idx % CP; int row = idx / CP;
    float v = (c < Cc) ? x[row*Cc + c] : 0.f;
    ws[OFF_XPAD + idx] = v;
  } else if (bid < 2940) {                // WcT: 768*84 = 64512
    int idx = (bid-2688)*256 + t;
    int c = idx % CP; int j = idx / CP;
    const float* wih = (j < TNH) ? wihf : wihb;
    const float* bih = (j < TNH) ? bihf : bihb;
    int jj = (j < TNH) ? j : j - TNH;
    float acc = 0.f;
    if (c < Cc) {
      for (int k = 0; k < NH; k++) acc = fmaf(wih[jj*NH+k], Wo[k*Cc + c], acc);
    } else if (c == Cc) {
      for (int k = 0; k < NH; k++) acc = fmaf(wih[jj*NH+k], bo[k], acc);
      acc += bih[jj];
    }
    ws[OFF_WCT + c*768 + j] = acc;
  } else if (bid < 3132) {                // whh4T: [dir][16][384][4] uints = 49152
    int idx = (bid-2940)*256 + t;
    int dir = idx / 24576;
    int r = idx % 24576;
    int u = r & 3;
    int tt = (r >> 2) % 384;            // row (output j)
    int k2g = (r >> 2) / 384;           // chunk
    int k2 = k2g*4 + u;                 // packed-half2 index along k
    const float* whh = dir ? whhb : whhf;
    float a = whh[tt*NH + 2*k2];
    float b = whh[tt*NH + 2*k2 + 1];
    union { _Float16 h[2]; unsigned int uu; } pk;
    pk.h[0] = (_Float16)a; pk.h[1] = (_Float16)b;
    ((unsigned int*)ws)[OFF_WHH2 + idx] = pk.uu;
  } else {                                // WqT/WkT: 2*16384
    int idx = (bid-3132)*256 + t;
    int j = idx & 127; int k = (idx >> 7) & 127; int w = idx >> 14;
    const float* W = w ? Wk : Wq;
    ws[(w ? OFF_WKT : OFF_WQT) + k*ET + j] = W[j*ET + k];
  }
}

// ---------------- K1: time-embed + projection ----------------
__global__ __launch_bounds__(256, 2) void k1_embed_proj(
    const float* __restrict__ query, const float* __restrict__ tsteps,
    const float* __restrict__ bq, const float* __restrict__ bk,
    float* ws) {
  __shared__ float emb[64*132];
  __shared__ float wt[64*132];
  int bid = blockIdx.x, t = threadIdx.x;
  bool isQ = bid < 64;
  int rowbase = isQ ? bid*64 : (bid-64)*64;

  for (int ii = 0; ii < 16; ii++) {
    int p = t + ii*256;
    int r = p >> 6, i = p & 63;
    int grow = rowbase + r;
    float pos = isQ ? query[grow] : tsteps[grow];
    float dv = __expf(-(float)(2*i) * (2.302585092994046f/128.f));
    float ang = 48.f * pos * dv;
    float sv, cv; __sincosf(ang, &sv, &cv);
    emb[r*132 + 2*i]     = sv;
    emb[r*132 + 2*i + 1] = cv;
  }

  const float* wtg  = ws + (isQ ? OFF_WQT : OFF_WKT);
  const float* bias = isQ ? bq : bk;
  int cq = t & 31, rh = t >> 5;
  float acc[8][4];
  for (int ri = 0; ri < 8; ri++)
    for (int u = 0; u < 4; u++) acc[ri][u] = bias[cq*4 + u];

  for (int kk = 0; kk < 128; kk += 64) {
    __syncthreads();
    for (int ii = 0; ii < 32; ii++) {
      int idx = t + ii*256;
      int kl = idx >> 7, j = idx & 127;
      wt[kl*132 + j] = wtg[(kk+kl)*ET + j];
    }
    __syncthreads();
    for (int k4 = 0; k4 < 16; k4++) {
      float wv[4][4];
      #pragma unroll
      for (int u = 0; u < 4; u++) {
        float4 w4 = *(const float4*)&wt[(k4*4+u)*132 + cq*4];
        wv[u][0]=w4.x; wv[u][1]=w4.y; wv[u][2]=w4.z; wv[u][3]=w4.w;
      }
      #pragma unroll
      for (int ri = 0; ri < 8; ri++) {
        float4 e4 = *(const float4*)&emb[(rh*8+ri)*132 + kk + k4*4];
        float ev[4] = {e4.x, e4.y, e4.z, e4.w};
        #pragma unroll
        for (int u = 0; u < 4; u++)
          #pragma unroll
          for (int jj = 0; jj < 4; jj++)
            acc[ri][jj] = fmaf(ev[u], wv[u][jj], acc[ri][jj]);
      }
    }
  }
  int secbase = isQ ? OFF_QALL : OFF_KALL;
  for (int ri = 0; ri < 8; ri++) {
    int grow = rowbase + rh*8 + ri;
    float4 o4 = {acc[ri][0], acc[ri][1], acc[ri][2], acc[ri][3]};
    *(float4*)&ws[secbase + grow*ET + cq*4] = o4;
  }
}

// ---------------- K2: attention (scores -> e -> S -> att) ----------------
__global__ __launch_bounds__(256, 2) void k2_attn(float* ws) {
  __shared__ float sS[16*CP];
  __shared__ float se[16*260];
  int bb = blockIdx.x >> 3, qt = blockIdx.x & 7;
  int t = threadIdx.x;
  int lane = t & 63, wv_ = t >> 6;
  int r4 = lane >> 2, seg = lane & 3;

  float4 qreg[8];
  const float* qrow = ws + OFF_QALL + (bb*LQn + qt*16 + r4)*ET + seg*32;
  #pragma unroll
  for (int u = 0; u < 8; u++) qreg[u] = *(const float4*)&qrow[u*4];

  const float* kb = ws + OFF_KALL + bb*LL*ET;
  #pragma unroll 2
  for (int l = wv_*64; l < wv_*64 + 64; l++) {
    const float* krow = kb + l*ET + seg*32;
    float a0=0.f, a1=0.f, a2=0.f, a3=0.f;
    #pragma unroll
    for (int u = 0; u < 8; u++) {
      float4 kv = *(const float4*)&krow[u*4];
      float* aa = (u&3)==0 ? &a0 : (u&3)==1 ? &a1 : (u&3)==2 ? &a2 : &a3;
      *aa = fmaf(qreg[u].x, kv.x, *aa);
      *aa = fmaf(qreg[u].y, kv.y, *aa);
      *aa = fmaf(qreg[u].z, kv.z, *aa);
      *aa = fmaf(qreg[u].w, kv.w, *aa);
    }
    float a = (a0+a1) + (a2+a3);
    a = quad_xor1_add(a);
    a = quad_xor2_add(a);
    if (seg == 0) se[r4*260 + l] = a;
  }
  __syncthreads();

  {
    int rr = t >> 4, j0 = t & 15;
    float m = -1e30f;
    for (int i = 0; i < 16; i++) m = fmaxf(m, se[rr*260 + j0 + 16*i]);
    for (int msk = 1; msk < 16; msk <<= 1) m = fmaxf(m, __shfl_xor(m, msk));
    for (int i = 0; i < 16; i++) {
      int c0 = j0 + 16*i;
      se[rr*260 + c0] = __expf((se[rr*260 + c0] - m) * 0.08838834764831845f);
    }
  }
  __syncthreads();

  int cq = t & 31, rg = t >> 5;
  if (cq < 21) {
    float acc[2][4] = {{0,0,0,0},{0,0,0,0}};
    const float* xb_ = ws + OFF_XPAD + bb*LL*CP;
    for (int l4 = 0; l4 < 64; l4++) {
      float4 e0 = *(const float4*)&se[(rg*2+0)*260 + l4*4];
      float4 e1 = *(const float4*)&se[(rg*2+1)*260 + l4*4];
      float ev[2][4] = {{e0.x,e0.y,e0.z,e0.w},{e1.x,e1.y,e1.z,e1.w}};
      #pragma unroll
      for (int v = 0; v < 4; v++) {
        float4 x4 = *(const float4*)&xb_[(l4*4+v)*CP + cq*4];
        float xv[4] = {x4.x,x4.y,x4.z,x4.w};
        #pragma unroll
        for (int ri = 0; ri < 2; ri++)
          #pragma unroll
          for (int cu = 0; cu < 4; cu++)
            acc[ri][cu] = fmaf(ev[ri][v], xv[cu], acc[ri][cu]);
      }
    }
    for (int ri = 0; ri < 2; ri++) {
      float4 o4 = {acc[ri][0],acc[ri][1],acc[ri][2],acc[ri][3]};
      *(float4*)&sS[(rg*2+ri)*CP + cq*4] = o4;
    }
  }
  __syncthreads();

  for (int idx = t; idx < 16*41; idx += 256) {
    int rr = idx / 41, c = idx % 41;
    sS[rr*CP + c] = sS[rr*CP + c] / sS[rr*CP + 41 + c];
  }
  __syncthreads();
  for (int idx = t; idx < 16*43; idx += 256) {
    int rr = idx / 43, c = 41 + idx % 43;
    sS[rr*CP + c] = (c < 83) ? 1.f : 0.f;
  }
  __syncthreads();
  int base = OFF_ATT + (bb*LQn + qt*16)*CP;
  for (int idx = t; idx < 16*CP; idx += 256) ws[base + idx] = sS[idx];
}

// ---------------- K3: xproj = att @ WcT ----------------
__global__ __launch_bounds__(256, 2) void k3_xproj(float* ws) {
  __shared__ float at[64*CP];
  int mblk = blockIdx.x / 6, jblk = blockIdx.x % 6;
  int t = threadIdx.x;
  for (int ii = 0; ii < 21; ii++) {
    int idx = t + ii*256;
    at[idx] = ws[OFF_ATT + mblk*64*CP + idx];
  }
  __syncthreads();
  int j4l = t & 31, rg = t >> 5;
  float acc[8][4] = {};
  const float* wct = ws + OFF_WCT;
  int jg = jblk*128 + j4l*4;
  for (int c4 = 0; c4 < 21; c4++) {
    float wv[4][4];
    #pragma unroll
    for (int u = 0; u < 4; u++) {
      float4 w4 = *(const float4*)&wct[(c4*4+u)*768 + jg];
      wv[u][0]=w4.x; wv[u][1]=w4.y; wv[u][2]=w4.z; wv[u][3]=w4.w;
    }
    #pragma unroll
    for (int ri = 0; ri < 8; ri++) {
      float4 a4 = *(const float4*)&at[(rg*8+ri)*CP + c4*4];
      float av[4] = {a4.x,a4.y,a4.z,a4.w};
      #pragma unroll
      for (int u = 0; u < 4; u++)
        #pragma unroll
        for (int jj = 0; jj < 4; jj++)
          acc[ri][jj] = fmaf(av[u], wv[u][jj], acc[ri][jj]);
    }
  }
  float* dst = ws + (jblk < 3 ? OFF_XF : OFF_XB);
  int col = (jblk % 3)*128 + j4l*4;
  for (int ri = 0; ri < 8; ri++) {
    int row = mblk*64 + rg*8 + ri;
    float4 o4 = {acc[ri][0],acc[ri][1],acc[ri][2],acc[ri][3]};
    *(float4*)&dst[row*TNH + col] = o4;
  }
}

// ---------------- K4: bidirectional GRU ----------------
// 64 blocks = (b, dir), 384 thr. Weights loaded ONCE into 16 uint4 and
// PINNED in VGPRs via asm (compiler can't rematerialize an asm-defined
// value -> zero weight loads on the serial critical path). One barrier per
// step, double-buffered gh, redundant per-wave gate math, x prefetched.
__global__ __launch_bounds__(384, 1) void k4_gru(
    const float* __restrict__ bhhf, const float* __restrict__ bhhb,
    float* ws) {
  __shared__ float gh[2][TNH];
  int bb = blockIdx.x >> 1, dir = blockIdx.x & 1;
  int t = threadIdx.x, lane = t & 63;
  int j0 = 2*lane;
  const uint4* wg4 = (const uint4*)((const unsigned int*)ws + OFF_WHH2 + dir*24576);
  const float* bhh = dir ? bhhb : bhhf;
  const float* xp = ws + (dir ? OFF_XB : OFF_XF) + bb*LQn*TNH;
  float* hc = ws + OFF_HCAT + bb*LQn*2*NH + dir*NH;

  // load weights once, then pin: asm-defined values cannot be remat'd
  uint4 w[16];
  #pragma unroll
  for (int c = 0; c < 16; c++) w[c] = wg4[c*384 + t];
  #pragma unroll
  for (int c = 0; c < 16; c++)
    asm volatile("" : "+v"(w[c].x), "+v"(w[c].y), "+v"(w[c].z), "+v"(w[c].w));

  float2 brv = *(const float2*)&bhh[j0];
  float2 bzv = *(const float2*)&bhh[NH + j0];
  float2 bnv = *(const float2*)&bhh[2*NH + j0];

  float h0 = 0.f, h1 = 0.f;
  unsigned int h2own = 0;

  int ti = dir ? (LQn-1) : 0;
  float2 xr = *(const float2*)&xp[ti*TNH + j0];
  float2 xz = *(const float2*)&xp[ti*TNH + NH + j0];
  float2 xn = *(const float2*)&xp[ti*TNH + 2*NH + j0];

  for (int step = 0; step < LQn; step++) {
    int buf = step & 1;

    // prefetch next step's x (consumed after NEXT barrier)
    int tin = dir ? (ti > 0 ? ti-1 : 0) : (ti < LQn-1 ? ti+1 : LQn-1);
    float2 xrn = *(const float2*)&xp[tin*TNH + j0];
    float2 xzn = *(const float2*)&xp[tin*TNH + NH + j0];
    float2 xnn = *(const float2*)&xp[tin*TNH + 2*NH + j0];

    // gh[t] = Whh[t,:] . h  — pure ALU (weights resident in VGPRs)
    float a0 = 0.f, a1 = 0.f;
    #pragma unroll
    for (int c = 0; c < 16; c++) {
      unsigned int hv0 = (unsigned int)__builtin_amdgcn_readlane((int)h2own, 4*c+0);
      unsigned int hv1 = (unsigned int)__builtin_amdgcn_readlane((int)h2own, 4*c+1);
      unsigned int hv2 = (unsigned int)__builtin_amdgcn_readlane((int)h2own, 4*c+2);
      unsigned int hv3 = (unsigned int)__builtin_amdgcn_readlane((int)h2own, 4*c+3);
      a0 = fdot2f(hv0, w[c].x, a0);
      a1 = fdot2f(hv1, w[c].y, a1);
      a0 = fdot2f(hv2, w[c].z, a0);
      a1 = fdot2f(hv3, w[c].w, a1);
    }
    gh[buf][t] = a0 + a1;

    __syncthreads();

    // gate math, redundant per-wave (j-pair 2*lane, 2*lane+1)
    float2 ghr = *(const float2*)&gh[buf][j0];
    float2 ghz = *(const float2*)&gh[buf][NH + j0];
    float2 ghn = *(const float2*)&gh[buf][2*NH + j0];

    float r0 = fast_sigmoid(xr.x + ghr.x + brv.x);
    float r1 = fast_sigmoid(xr.y + ghr.y + brv.y);
    float z0 = fast_sigmoid(xz.x + ghz.x + bzv.x);
    float z1 = fast_sigmoid(xz.y + ghz.y + bzv.y);
    float n0 = fast_tanh(xn.x + r0*(ghn.x + bnv.x));
    float n1 = fast_tanh(xn.y + r1*(ghn.y + bnv.y));
    h0 = (1.f - z0)*n0 + z0*h0;
    h1 = (1.f - z1)*n1 + z1*h1;

    union { _Float16 h[2]; unsigned int u; } pk;
    pk.h[0] = (_Float16)h0; pk.h[1] = (_Float16)h1;
    h2own = pk.u;

    if (t < 64) {
      float2 o2 = {h0, h1};
      *(float2*)&hc[ti*2*NH + j0] = o2;
    }

    xr = xrn; xz = xzn; xn = xnn;
    ti = tin;
  }
}

// ---------------- K5: final MLP ----------------
__global__ __launch_bounds__(256, 2) void k5_mlp(
    const float* __restrict__ W1, const float* __restrict__ b1,
    const float* __restrict__ W2, const float* __restrict__ b2,
    const float* __restrict__ ws, float* __restrict__ out) {
  __shared__ float hl[32*264];
  __shared__ float hid[32*52];
  int t = threadIdx.x;
  int rowbase = blockIdx.x * 32;
  for (int ii = 0; ii < 32; ii++) {
    int idx = t + ii*256;
    int r = idx >> 8, c = idx & 255;
    hl[r*264 + c] = ws[OFF_HCAT + (rowbase + r)*256 + c];
  }
  __syncthreads();
  int r = t & 31, mg = t >> 5;
  float acc[7];
  #pragma unroll
  for (int im = 0; im < 7; im++) {
    int m = mg + 8*im;
    acc[im] = (m < 50) ? b1[m] : 0.f;
  }
  for (int k4 = 0; k4 < 64; k4++) {
    float4 h4 = *(const float4*)&hl[r*264 + k4*4];
    #pragma unroll
    for (int im = 0; im < 7; im++) {
      int m = mg + 8*im;
      if (m < 50) {
        float4 w4 = *(const float4*)&W1[m*256 + k4*4];
        acc[im] = fmaf(h4.x, w4.x, acc[im]);
        acc[im] = fmaf(h4.y, w4.y, acc[im]);
        acc[im] = fmaf(h4.z, w4.z, acc[im]);
        acc[im] = fmaf(h4.w, w4.w, acc[im]);
      }
    }
  }
  #pragma unroll
  for (int im = 0; im < 7; im++) {
    int m = mg + 8*im;
    if (m < 50) hid[r*52 + m] = fmaxf(acc[im], 0.f);
  }
  __syncthreads();
  int og = mg;
  float a4[4];
  #pragma unroll
  for (int u = 0; u < 4; u++) a4[u] = b2[og*4 + u];
  for (int m = 0; m < 50; m++) {
    float hv = hid[r*52 + m];
    #pragma unroll
    for (int u = 0; u < 4; u++)
      a4[u] = fmaf(hv, W2[(og*4+u)*50 + m], a4[u]);
  }
  float4 o4 = {a4[0], a4[1], a4[2], a4[3]};
  *(float4*)&out[(rowbase + r)*32 + og*4] = o4;
}

extern "C" void kernel_launch(void* const* d_in, const int* in_sizes, int n_in,
                              void* d_out, int out_size, void* d_ws, size_t ws_size,
                              hipStream_t stream) {
  (void)in_sizes; (void)n_in; (void)out_size; (void)ws_size;
  const float* x      = (const float*)d_in[0];
  const float* tsteps = (const float*)d_in[1];
  const float* query  = (const float*)d_in[2];
  const float* Wq     = (const float*)d_in[3];
  const float* bq     = (const float*)d_in[4];
  const float* Wk     = (const float*)d_in[5];
  const float* bk     = (const float*)d_in[6];
  const float* Wo     = (const float*)d_in[7];
  const float* bo     = (const float*)d_in[8];
  const float* wihf   = (const float*)d_in[9];
  const float* whhf   = (const float*)d_in[10];
  const float* bihf   = (const float*)d_in[11];
  const float* bhhf   = (const float*)d_in[12];
  const float* wihb   = (const float*)d_in[13];
  const float* whhb   = (const float*)d_in[14];
  const float* bihb   = (const float*)d_in[15];
  const float* bhhb   = (const float*)d_in[16];
  const float* W1     = (const float*)d_in[17];
  const float* b1     = (const float*)d_in[18];
  const float* W2     = (const float*)d_in[19];
  const float* b2     = (const float*)d_in[20];
  float* ws = (float*)d_ws;

  k0_prep<<<3260, 256, 0, stream>>>(x, Wq, Wk, Wo, bo, wihf, bihf, wihb, bihb, whhf, whhb, ws);
  k1_embed_proj<<<192, 256, 0, stream>>>(query, tsteps, bq, bk, ws);
  k2_attn<<<256, 256, 0, stream>>>(ws);
  k3_xproj<<<384, 256, 0, stream>>>(ws);
  k4_gru<<<64, 384, 0, stream>>>(bhhf, bhhb, ws);
  k5_mlp<<<128, 256, 0, stream>>>(W1, b1, W2, b2, ws, (float*)d_out);
}